// Round 9
// baseline (157.741 us; speedup 1.0000x reference)
//
#include <hip/hip_runtime.h>

#define GRID_R 128
#define PLANE (GRID_R * GRID_R)
#define NVOX (GRID_R * GRID_R * GRID_R)
#define NB 8            // bins = XCDs; oct slice per bin = 4 MiB = per-XCD L2
#define BINSHIFT 19     // idx in [0, 2*NVOX) = 2^22 -> >>19 gives 8 bins

typedef float vfloat4 __attribute__((ext_vector_type(4)));
typedef float vfloat2 __attribute__((ext_vector_type(2)));
typedef unsigned int u32;
typedef unsigned long long u64;

// ---- fused build: BOTH fp32 volumes -> one contiguous oct-texel u64 buffer.
// O[cell] = 8 corner u8 values of cell, bytes (dz,dy,dx). All reads clamped.
// Also zeroes the NB bin cursors (block 0).
__global__ __launch_bounds__(256) void build_oct2_kernel(
    const float* __restrict__ vyin, const float* __restrict__ vyang,
    u64* __restrict__ oct, u32* __restrict__ cursors)
{
    int t = blockIdx.x * blockDim.x + threadIdx.x;  // 2*NVOX threads
    if (t < NB) cursors[t] = 0u;

    const float* __restrict__ vol = (t < NVOX) ? vyin : vyang;
    int c = t & (NVOX - 1);
    int x = c & 127, y = (c >> 7) & 127, z = c >> 14;
    int xr = min(x, 126);
    bool xe = (x == 127);
    int y1 = min(y + 1, 127), z1 = min(z + 1, 127);

    const float* r00 = vol + (size_t)z * PLANE + (size_t)y * GRID_R + xr;
    const float* r01 = vol + (size_t)z * PLANE + (size_t)y1 * GRID_R + xr;
    const float* r10 = vol + (size_t)z1 * PLANE + (size_t)y * GRID_R + xr;
    const float* r11 = vol + (size_t)z1 * PLANE + (size_t)y1 * GRID_R + xr;

    vfloat2 p00 = *reinterpret_cast<const vfloat2*>(r00);
    vfloat2 p01 = *reinterpret_cast<const vfloat2*>(r01);
    vfloat2 p10 = *reinterpret_cast<const vfloat2*>(r10);
    vfloat2 p11 = *reinterpret_cast<const vfloat2*>(r11);

    float a00 = xe ? p00.y : p00.x, b00 = p00.y;
    float a01 = xe ? p01.y : p01.x, b01 = p01.y;
    float a10 = xe ? p10.y : p10.x, b10 = p10.y;
    float a11 = xe ? p11.y : p11.x, b11 = p11.y;

    u32 q000 = (u32)(a00 * 255.0f + 0.5f), q001 = (u32)(b00 * 255.0f + 0.5f);
    u32 q010 = (u32)(a01 * 255.0f + 0.5f), q011 = (u32)(b01 * 255.0f + 0.5f);
    u32 q100 = (u32)(a10 * 255.0f + 0.5f), q101 = (u32)(b10 * 255.0f + 0.5f);
    u32 q110 = (u32)(a11 * 255.0f + 0.5f), q111 = (u32)(b11 * 255.0f + 0.5f);

    u32 lo = q000 | (q001 << 8) | (q010 << 16) | (q011 << 24);
    u32 hi = q100 | (q101 << 8) | (q110 << 16) | (q111 << 24);
    oct[t] = (u64)lo | ((u64)hi << 32);
}

// ---- shared prep: sample -> (cell idx incl. volume offset, 3 weights) ----
__device__ __forceinline__ void prep_sample(
    const float* __restrict__ s, u32* idx, float* w)
{
    vfloat4 A = __builtin_nontemporal_load(reinterpret_cast<const vfloat4*>(s));      // s0..s3
    vfloat4 B = __builtin_nontemporal_load(reinterpret_cast<const vfloat4*>(s + 3));  // s3..s6

    bool yin = (B.w == 0.0f);   // flag
    float cx = yin ? A.x : B.x;
    float cy = yin ? A.y : B.y;
    float cz = yin ? A.z : B.z;

    float x = (cx + 1.0f) * 0.5f * 127.0f;
    float y = (cy + 1.0f) * 0.5f * 127.0f;
    float z = (cz + 1.0f) * 0.5f * 127.0f;

    float fx = fminf(fmaxf(floorf(x), 0.0f), 127.0f);
    float fy = fminf(fmaxf(floorf(y), 0.0f), 127.0f);
    float fz = fminf(fmaxf(floorf(z), 0.0f), 127.0f);

    w[0] = x - fx;
    w[1] = y - fy;
    w[2] = z - fz;

    *idx = (u32)((int)fz * PLANE + (int)fy * GRID_R + (int)fx)
         + (yin ? 0u : (u32)NVOX);
}

__device__ __forceinline__ float combine(u64 q, float wx, float wy, float wz)
{
    u32 lo = (u32)q, hi = (u32)(q >> 32);
    float c000 = (float)(lo & 0xff),         c001 = (float)((lo >> 8) & 0xff);
    float c010 = (float)((lo >> 16) & 0xff), c011 = (float)(lo >> 24);
    float c100 = (float)(hi & 0xff),         c101 = (float)((hi >> 8) & 0xff);
    float c110 = (float)((hi >> 16) & 0xff), c111 = (float)(hi >> 24);
    float c00 = c000 + (c001 - c000) * wx;
    float c01 = c010 + (c011 - c010) * wx;
    float c10 = c100 + (c101 - c100) * wx;
    float c11 = c110 + (c111 - c110) * wx;
    float c0 = c00 + (c01 - c00) * wy;
    float c1 = c10 + (c11 - c10) * wy;
    return (c0 + (c1 - c0) * wz) * (1.0f / 255.0f);
}

#define ILP 4

// ---- Pass A: scatter samples into NB bin segments (SoA records).
// Record = (idx, orig, wq[3x10b]). Slot reservation: LDS hist per block +
// one global atomicAdd per (block,bin). Record ORDER in a bin is
// nondeterministic; every record's computation and out[orig] target are
// order-independent -> output is bit-deterministic.
template <bool EXACT>
__global__ __launch_bounds__(256, 8) void scatter_kernel(
    const float* __restrict__ ns, int n, u32 cap,
    u32* __restrict__ idxA, u32* __restrict__ origA, u32* __restrict__ wA,
    u32* __restrict__ cursors)
{
    __shared__ u32 hist[NB];
    __shared__ u32 base[NB];
    const int T = gridDim.x * blockDim.x;
    const int i0 = blockIdx.x * blockDim.x + threadIdx.x;

    if (threadIdx.x < NB) hist[threadIdx.x] = 0u;
    __syncthreads();

    u32 idx[ILP], wq[ILP], ord[ILP];
    #pragma unroll
    for (int k = 0; k < ILP; ++k) {
        int i = i0 + k * T;
        if (EXACT || i < n) {
            float w[3];
            prep_sample(ns + (size_t)i * 7, &idx[k], w);
            wq[k] = (u32)(w[0] * 1023.0f + 0.5f)
                  | ((u32)(w[1] * 1023.0f + 0.5f) << 10)
                  | ((u32)(w[2] * 1023.0f + 0.5f) << 20);
            ord[k] = atomicAdd(&hist[idx[k] >> BINSHIFT], 1u);
        }
    }
    __syncthreads();
    if (threadIdx.x < NB)
        base[threadIdx.x] = atomicAdd(&cursors[threadIdx.x], hist[threadIdx.x]);
    __syncthreads();

    #pragma unroll
    for (int k = 0; k < ILP; ++k) {
        int i = i0 + k * T;
        if (EXACT || i < n) {
            u32 bin = idx[k] >> BINSHIFT;
            u32 slot = bin * cap + base[bin] + ord[k];
            idxA[slot] = idx[k];
            origA[slot] = (u32)i;
            wA[slot] = wq[k];
        }
    }
}

// ---- Pass B: binned gather. Block b -> bin b%NB; round-robin dispatch puts
// all of bin j's blocks on XCD j, so the bin's 4 MiB oct slice stays L2-hot.
__global__ __launch_bounds__(256, 8) void binned_main_kernel(
    const u64* __restrict__ oct,
    const u32* __restrict__ idxA, const u32* __restrict__ origA,
    const u32* __restrict__ wA, const u32* __restrict__ cursors,
    u32 cap, float* __restrict__ out)
{
    const u32 j = blockIdx.x & (NB - 1);
    const u32 chunk = blockIdx.x >> 3;            // 0..chunksPerBin-1
    const u32 TB = (gridDim.x >> 3) * blockDim.x; // threads per bin
    const u32 cnt = cursors[j];                   // records in bin j
    const u32 rec0 = j * cap;

    for (u32 r = chunk * blockDim.x + threadIdx.x; r < cnt; r += 4 * TB) {
        u32 rr[4];
        bool ok[4];
        u32 idx[4], orig[4], wq[4];
        #pragma unroll
        for (int k = 0; k < 4; ++k) {
            rr[k] = r + (u32)k * TB;
            ok[k] = rr[k] < cnt;
            u32 rd = ok[k] ? (rec0 + rr[k]) : rec0;
            idx[k]  = __builtin_nontemporal_load(idxA + rd);
            orig[k] = __builtin_nontemporal_load(origA + rd);
            wq[k]   = __builtin_nontemporal_load(wA + rd);
        }
        u64 q[4];
        #pragma unroll
        for (int k = 0; k < 4; ++k) q[k] = oct[idx[k]];
        #pragma unroll
        for (int k = 0; k < 4; ++k) {
            if (ok[k]) {
                float wx = (float)(wq[k] & 1023u) * (1.0f / 1023.0f);
                float wy = (float)((wq[k] >> 10) & 1023u) * (1.0f / 1023.0f);
                float wz = (float)((wq[k] >> 20) & 1023u) * (1.0f / 1023.0f);
                __builtin_nontemporal_store(combine(q[k], wx, wy, wz), out + orig[k]);
            }
        }
    }
}

// ---- r8 one-pass oct kernel (fallback when ws fits oct only) ----
template <bool EXACT>
__global__ __launch_bounds__(256, 8) void yy_oct_kernel(
    const float* __restrict__ ns, const u64* __restrict__ oct,
    float* __restrict__ out, int n)
{
    const int T = gridDim.x * blockDim.x;
    const int i0 = blockIdx.x * blockDim.x + threadIdx.x;

    u32 idx[ILP];
    float w[ILP][3];
    #pragma unroll
    for (int k = 0; k < ILP; ++k) {
        int i = i0 + k * T;
        if (EXACT || i < n) {
            prep_sample(ns + (size_t)i * 7, &idx[k], w[k]);
        } else {
            idx[k] = 0; w[k][0] = w[k][1] = w[k][2] = 0.0f;
        }
    }
    u64 q[ILP];
    #pragma unroll
    for (int k = 0; k < ILP; ++k) q[k] = oct[idx[k]];
    #pragma unroll
    for (int k = 0; k < ILP; ++k) {
        int i = i0 + k * T;
        if (EXACT || i < n) {
            __builtin_nontemporal_store(
                combine(q[k], w[k][0], w[k][1], w[k][2]), out + i);
        }
    }
}

// ---- fp32 ultimate fallback ----
__global__ __launch_bounds__(256) void yy_f32_kernel(
    const float* __restrict__ ns, const float* __restrict__ vyin,
    const float* __restrict__ vyang, float* __restrict__ out, int n)
{
    const int stride = gridDim.x * blockDim.x;
    for (int i = blockIdx.x * blockDim.x + threadIdx.x; i < n; i += stride) {
        const float* s = ns + (size_t)i * 7;
        float s0 = s[0], s1 = s[1], s2 = s[2], s3 = s[3], s4 = s[4], s5 = s[5], flag = s[6];
        bool yin = (flag == 0.0f);
        float cx = yin ? s0 : s3, cy = yin ? s1 : s4, cz = yin ? s2 : s5;
        const float* __restrict__ vol = yin ? vyin : vyang;
        float x = (cx + 1.0f) * 0.5f * 127.0f;
        float y = (cy + 1.0f) * 0.5f * 127.0f;
        float z = (cz + 1.0f) * 0.5f * 127.0f;
        float fx = fminf(fmaxf(floorf(x), 0.0f), 127.0f);
        float fy = fminf(fmaxf(floorf(y), 0.0f), 127.0f);
        float fz = fminf(fmaxf(floorf(z), 0.0f), 127.0f);
        int x0 = (int)fx, y0 = (int)fy, z0 = (int)fz;
        int x1 = min(x0 + 1, 127), y1 = min(y0 + 1, 127), z1 = min(z0 + 1, 127);
        float wx = x - fx, wy = y - fy, wz = z - fz;
        int zy00 = z0 * PLANE + y0 * GRID_R, zy01 = z0 * PLANE + y1 * GRID_R;
        int zy10 = z1 * PLANE + y0 * GRID_R, zy11 = z1 * PLANE + y1 * GRID_R;
        float c000 = vol[zy00 + x0], c001 = vol[zy00 + x1];
        float c010 = vol[zy01 + x0], c011 = vol[zy01 + x1];
        float c100 = vol[zy10 + x0], c101 = vol[zy10 + x1];
        float c110 = vol[zy11 + x0], c111 = vol[zy11 + x1];
        float c00 = c000 + (c001 - c000) * wx, c01 = c010 + (c011 - c010) * wx;
        float c10 = c100 + (c101 - c100) * wx, c11 = c110 + (c111 - c110) * wx;
        float c0 = c00 + (c01 - c00) * wy, c1 = c10 + (c11 - c10) * wy;
        out[i] = c0 + (c1 - c0) * wz;
    }
}

extern "C" void kernel_launch(void* const* d_in, const int* in_sizes, int n_in,
                              void* d_out, int out_size, void* d_ws, size_t ws_size,
                              hipStream_t stream) {
    const float* ns    = (const float*)d_in[0];
    const float* vyin  = (const float*)d_in[1];
    const float* vyang = (const float*)d_in[2];
    float* out = (float*)d_out;
    int n = out_size;

    const size_t OCT_BYTES = (size_t)16 * NVOX;          // 32 MiB
    const u32 cap = (u32)(n / NB) + 65536u;              // bin capacity (+~96 sigma)
    const size_t REC_BYTES = (size_t)3 * NB * cap * 4;   // SoA idx/orig/wq
    const size_t need_binned = OCT_BYTES + REC_BYTES + 256;

    int threads_needed = (n + ILP - 1) / ILP;
    int grid = (threads_needed + 255) / 256;             // n=4194304 -> 4096
    bool exact = ((long long)grid * 256 * ILP == (long long)n);

    if (ws_size >= need_binned && (grid & (NB - 1)) == 0) {
        u64* oct   = (u64*)d_ws;
        u32* idxA  = (u32*)((char*)d_ws + OCT_BYTES);
        u32* origA = idxA + (size_t)NB * cap;
        u32* wA    = origA + (size_t)NB * cap;
        u32* cursors = wA + (size_t)NB * cap;

        build_oct2_kernel<<<2 * NVOX / 256, 256, 0, stream>>>(vyin, vyang, oct, cursors);
        if (exact)
            scatter_kernel<true><<<grid, 256, 0, stream>>>(ns, n, cap, idxA, origA, wA, cursors);
        else
            scatter_kernel<false><<<grid, 256, 0, stream>>>(ns, n, cap, idxA, origA, wA, cursors);
        binned_main_kernel<<<grid, 256, 0, stream>>>(oct, idxA, origA, wA, cursors, cap, out);
    } else if (ws_size >= OCT_BYTES) {
        u64* oct = (u64*)d_ws;
        u32* dummy_cursors = (u64*)d_ws == nullptr ? nullptr : (u32*)d_ws;  // unused safely
        build_oct2_kernel<<<2 * NVOX / 256, 256, 0, stream>>>(vyin, vyang, oct, (u32*)d_ws);
        if (exact)
            yy_oct_kernel<true><<<grid, 256, 0, stream>>>(ns, oct, out, n);
        else
            yy_oct_kernel<false><<<grid, 256, 0, stream>>>(ns, oct, out, n);
        (void)dummy_cursors;
    } else {
        yy_f32_kernel<<<2048, 256, 0, stream>>>(ns, vyin, vyang, out, n);
    }
}

// Round 10
// 99.112 us; speedup vs baseline: 1.5915x; 1.5915x over previous
//
#include <hip/hip_runtime.h>

#define GRID_R 128
#define PLANE (GRID_R * GRID_R)
#define NVOX (GRID_R * GRID_R * GRID_R)
#define SPB 1024              // samples per block
#define ILP 4                 // 256 threads x 4 samples

typedef float vfloat4 __attribute__((ext_vector_type(4)));
typedef unsigned int u32;

// ---- build: BOTH fp32 volumes -> one contiguous 4 MiB u8 buffer.
// q = round(v*255), v in [0,1): err <= 1/510.
__global__ __launch_bounds__(256) void cvt_u8_2_kernel(
    const float* __restrict__ vyin, const float* __restrict__ vyang,
    unsigned char* __restrict__ u8v)
{
    int t = blockIdx.x * blockDim.x + threadIdx.x;   // 2*NVOX/4 threads
    bool yin = (t < NVOX / 4);
    const float* src = yin ? vyin : vyang;
    int c = yin ? t : t - NVOX / 4;
    vfloat4 v = *reinterpret_cast<const vfloat4*>(src + (size_t)c * 4);
    uchar4 q;
    q.x = (unsigned char)(v.x * 255.0f + 0.5f);
    q.y = (unsigned char)(v.y * 255.0f + 0.5f);
    q.z = (unsigned char)(v.z * 255.0f + 0.5f);
    q.w = (unsigned char)(v.w * 255.0f + 0.5f);
    reinterpret_cast<uchar4*>(u8v)[t] = q;
}

__device__ __forceinline__ float combine4(const unsigned short* v,
                                          float wx, float wy, float wz)
{
    float lo0 = (float)(v[0] & 0xff), hi0 = (float)(v[0] >> 8);
    float lo1 = (float)(v[1] & 0xff), hi1 = (float)(v[1] >> 8);
    float lo2 = (float)(v[2] & 0xff), hi2 = (float)(v[2] >> 8);
    float lo3 = (float)(v[3] & 0xff), hi3 = (float)(v[3] >> 8);
    float c00 = lo0 + (hi0 - lo0) * wx;
    float c01 = lo1 + (hi1 - lo1) * wx;
    float c10 = lo2 + (hi2 - lo2) * wx;
    float c11 = lo3 + (hi3 - lo3) * wx;
    float c0 = c00 + (c01 - c00) * wy;
    float c1 = c10 + (c11 - c10) * wy;
    return (c0 + (c1 - c0) * wz) * (1.0f / 255.0f);
}

// ---- main: LDS-coalesced stream + 4 paired-u16 L2-resident gathers ----
template <bool EXACT>
__global__ __launch_bounds__(256, 5) void yy_lds_kernel(
    const float* __restrict__ ns, const unsigned char* __restrict__ u8v,
    float* __restrict__ out, int n)
{
    __shared__ __align__(16) float lds[SPB * 7];   // 28 KiB
    const int tid = threadIdx.x;
    const long long sbase = (long long)blockIdx.x * SPB;  // first sample of block

    // Phase 0: coalesced nontemporal stage of 1024 samples (28 KB) into LDS.
    if (EXACT) {
        const vfloat4* src4 = reinterpret_cast<const vfloat4*>(ns + sbase * 7);
        vfloat4* dst4 = reinterpret_cast<vfloat4*>(lds);
        #pragma unroll
        for (int j = 0; j < 7; ++j) {
            int e = j * 256 + tid;   // 1792 float4s
            dst4[e] = __builtin_nontemporal_load(src4 + e);
        }
    } else {
        long long cnt = (long long)n - sbase;            // samples this block
        if (cnt > SPB) cnt = SPB;
        int nf = (int)(cnt * 7);
        const float* srcf = ns + sbase * 7;
        for (int j = tid; j < nf; j += 256) lds[j] = srcf[j];
    }
    __syncthreads();

    // Phase 1: per-sample prep from LDS (stride-7 reads: <=2-way bank alias, free)
    u32 a[ILP][4];
    float w[ILP][3];
    #pragma unroll
    for (int k = 0; k < ILP; ++k) {
        int l = tid + k * 256;
        if (EXACT || sbase + l < n) {
            const float* s = lds + l * 7;
            float s0 = s[0], s1 = s[1], s2 = s[2];
            float s3 = s[3], s4 = s[4], s5 = s[5];
            float flag = s[6];
            bool yin = (flag == 0.0f);
            float cx = yin ? s0 : s3;
            float cy = yin ? s1 : s4;
            float cz = yin ? s2 : s5;

            float x = (cx + 1.0f) * 0.5f * 127.0f;
            float y = (cy + 1.0f) * 0.5f * 127.0f;
            float z = (cz + 1.0f) * 0.5f * 127.0f;
            float fx = fminf(fmaxf(floorf(x), 0.0f), 127.0f);
            float fy = fminf(fmaxf(floorf(y), 0.0f), 127.0f);
            float fz = fminf(fmaxf(floorf(z), 0.0f), 127.0f);
            int x0 = (int)fx, y0 = (int)fy, z0 = (int)fz;
            int dy = (y0 < 127) ? GRID_R : 0;
            int dz = (z0 < 127) ? PLANE : 0;

            w[k][0] = x - fx;
            w[k][1] = y - fy;
            w[k][2] = z - fz;

            u32 base = (u32)(z0 * PLANE + y0 * GRID_R + x0) + (yin ? 0u : (u32)NVOX);
            a[k][0] = base;
            a[k][1] = base + dy;
            a[k][2] = base + dz;
            a[k][3] = base + dz + dy;
            // u16 at each addr -> (v[x0], v[x0+1]); x0==127 high byte is garbage
            // but wx==0 exactly -> weight 0 (finite, no NaN). 1B overrun padded.
        } else {
            a[k][0] = a[k][1] = a[k][2] = a[k][3] = 0;
            w[k][0] = w[k][1] = w[k][2] = 0.0f;
        }
    }

    // Phase 2: all 16 u16 gathers in flight (L2-resident 4 MiB working set)
    unsigned short v[ILP][4];
    #pragma unroll
    for (int k = 0; k < ILP; ++k) {
        #pragma unroll
        for (int j = 0; j < 4; ++j) {
            v[k][j] = *reinterpret_cast<const unsigned short*>(u8v + a[k][j]);
        }
    }

    // Phase 3: combine + coalesced nontemporal store
    #pragma unroll
    for (int k = 0; k < ILP; ++k) {
        int l = tid + k * 256;
        if (EXACT || sbase + l < n) {
            __builtin_nontemporal_store(
                combine4(v[k], w[k][0], w[k][1], w[k][2]), out + sbase + l);
        }
    }
}

// ---- fp32 fallback (only if ws too small; not expected) ----
__global__ __launch_bounds__(256) void yy_f32_kernel(
    const float* __restrict__ ns, const float* __restrict__ vyin,
    const float* __restrict__ vyang, float* __restrict__ out, int n)
{
    const int stride = gridDim.x * blockDim.x;
    for (int i = blockIdx.x * blockDim.x + threadIdx.x; i < n; i += stride) {
        const float* s = ns + (size_t)i * 7;
        float s0 = s[0], s1 = s[1], s2 = s[2], s3 = s[3], s4 = s[4], s5 = s[5], flag = s[6];
        bool yin = (flag == 0.0f);
        float cx = yin ? s0 : s3, cy = yin ? s1 : s4, cz = yin ? s2 : s5;
        const float* __restrict__ vol = yin ? vyin : vyang;
        float x = (cx + 1.0f) * 0.5f * 127.0f;
        float y = (cy + 1.0f) * 0.5f * 127.0f;
        float z = (cz + 1.0f) * 0.5f * 127.0f;
        float fx = fminf(fmaxf(floorf(x), 0.0f), 127.0f);
        float fy = fminf(fmaxf(floorf(y), 0.0f), 127.0f);
        float fz = fminf(fmaxf(floorf(z), 0.0f), 127.0f);
        int x0 = (int)fx, y0 = (int)fy, z0 = (int)fz;
        int x1 = min(x0 + 1, 127), y1 = min(y0 + 1, 127), z1 = min(z0 + 1, 127);
        float wx = x - fx, wy = y - fy, wz = z - fz;
        int zy00 = z0 * PLANE + y0 * GRID_R, zy01 = z0 * PLANE + y1 * GRID_R;
        int zy10 = z1 * PLANE + y0 * GRID_R, zy11 = z1 * PLANE + y1 * GRID_R;
        float c000 = vol[zy00 + x0], c001 = vol[zy00 + x1];
        float c010 = vol[zy01 + x0], c011 = vol[zy01 + x1];
        float c100 = vol[zy10 + x0], c101 = vol[zy10 + x1];
        float c110 = vol[zy11 + x0], c111 = vol[zy11 + x1];
        float c00 = c000 + (c001 - c000) * wx, c01 = c010 + (c011 - c010) * wx;
        float c10 = c100 + (c101 - c100) * wx, c11 = c110 + (c111 - c110) * wx;
        float c0 = c00 + (c01 - c00) * wy, c1 = c10 + (c11 - c10) * wy;
        out[i] = c0 + (c1 - c0) * wz;
    }
}

extern "C" void kernel_launch(void* const* d_in, const int* in_sizes, int n_in,
                              void* d_out, int out_size, void* d_ws, size_t ws_size,
                              hipStream_t stream) {
    const float* ns    = (const float*)d_in[0];
    const float* vyin  = (const float*)d_in[1];
    const float* vyang = (const float*)d_in[2];
    float* out = (float*)d_out;
    int n = out_size;

    size_t need = (size_t)2 * NVOX + 64;   // 4 MiB u8 (both vols) + u16 overrun slack
    if (ws_size >= need) {
        unsigned char* u8v = (unsigned char*)d_ws;
        cvt_u8_2_kernel<<<2 * NVOX / 4 / 256, 256, 0, stream>>>(vyin, vyang, u8v);
        int grid = (int)(((long long)n + SPB - 1) / SPB);   // N=4194304 -> 4096
        if ((long long)grid * SPB == (long long)n)
            yy_lds_kernel<true><<<grid, 256, 0, stream>>>(ns, u8v, out, n);
        else
            yy_lds_kernel<false><<<grid, 256, 0, stream>>>(ns, u8v, out, n);
    } else {
        yy_f32_kernel<<<2048, 256, 0, stream>>>(ns, vyin, vyang, out, n);
    }
}